// Round 15
// baseline (314.611 us; speedup 1.0000x reference)
//
#include <hip/hip_runtime.h>

// CRF fixed-point: the map q <- sigmoid(x + avg3x3(q)) is a 1/4-contraction in
// L_inf (sigmoid' <= 1/4, kernel row-sum <= 1), and ||q0 - q*|| <= 1/4.
// CRF1 4 iters: ||q4 - q*|| <= (1/4)^5 ~ 1e-3 (measured absmax 0.0156 at the
// output, threshold 0.0534). CRF2 4 iters adds <= ~2e-3 worst-case.
#define CRF1_ITERS 4
#define CRF2_ITERS 4

#define LOG2E 1.44269504f
#define C9    (-LOG2E / 9.0f)

#if __has_builtin(__builtin_amdgcn_exp2f)
#define EXP2F(x) __builtin_amdgcn_exp2f(x)
#else
#define EXP2F(x) exp2f(x)
#endif
#if __has_builtin(__builtin_amdgcn_rcpf)
#define RCPF(x) __builtin_amdgcn_rcpf(x)
#else
#define RCPF(x) __fdividef(1.0f, (x))
#endif

__device__ __forceinline__ float sigq(float s, float xs) {
    return RCPF(1.0f + EXP2F(fmaf(s, C9, xs)));
}
__device__ __forceinline__ float sigm(float v) {
    return __fdividef(1.0f, 1.0f + __expf(-v));
}
__device__ __forceinline__ float max3f(float a, float b, float c) {
    return fmaxf(fmaxf(a, b), c);
}

// ---------------------------------------------------------------------------
// Kernel 1 v3: conv1(5x5)+BN1 + sigmoid-CRF(4 it) + maxpool 3x3/3.
// ONE channel per 512-thread block (grid 4096). LDS cut 64KB -> 34KB to get
// 4 blocks/CU (32 waves = cap): the 2-block version (round 13/14, 129 us)
// was ~60us of barrier/DS lockstep stall over a ~67us VALU+trans floor.
//  - NO input staging: conv windows read direct from global (coalesced 1KB
//    per wave per row; image is L2-resident, shared by 32 channel-blocks).
//  - NO pool buffer: vertical 3-row maxes computed in registers; only a
//    41x132 vmax plane + 16x132 boundary-aux live in LDS, reusing the dead
//    halo region. Boundary pool rows (3 rows spanning two strips) combine
//    main (bottom-partial owner) + aux[s2] (top-partial owner).
// LDS (8704 floats): halo hb0@0, hb1@4352 (34 rows x 128; strip S writes h
// rows at 2S+1/2S+2, guards 0/33); after iters: vmax[41][132]@0, aux[16][132]
// @5412.
// ---------------------------------------------------------------------------
#define HBSZ 4352
#define AUXO 5412

__attribute__((amdgpu_flat_work_group_size(512, 512), amdgpu_waves_per_eu(4)))
__global__ void k1_conv_crf_pool(
    const float* __restrict__ xin,   // [128,1,128,128]
    const float* __restrict__ w1,    // [32,1,5,5]
    const float* __restrict__ b1,
    const float* __restrict__ g1,
    const float* __restrict__ be1,
    const float* __restrict__ m1,
    const float* __restrict__ v1,
    float* __restrict__ mp1)         // [128,32,41,41]
{
    __shared__ float smem[8704];     // 34 KB

    const int blk = blockIdx.x;      // b*32 + oc
    const int b   = blk >> 5;
    const int oc  = blk & 31;
    const int tid = threadIdx.x;
    const int ln  = tid & 63;
    const int S   = tid >> 5;        // strip 0..15, rows S*8 .. S*8+7
    const int qcl = tid & 31;        // 0..31 (31 = idle)
    const bool colAct = (qcl < 31);
    const int qc  = colAct ? qcl : 30;   // clamped for addressing
    const int r0  = S * 8;

    const float A  = g1[oc] * rsqrtf(v1[oc] + 1e-5f);
    const float Bc = (b1[oc] - m1[oc]) * A + be1[oc];
    float wreg[25];
    #pragma unroll
    for (int k = 0; k < 25; ++k) wreg[k] = w1[oc * 25 + k] * A;

    // ---- conv 5x5 VALID + folded BN, windows direct from global ----
    const float* img = xin + (size_t)b * 16384;
    float xs[8][4];
    #pragma unroll
    for (int r = 0; r < 8; ++r)
        #pragma unroll
        for (int c = 0; c < 4; ++c) xs[r][c] = Bc;
    #pragma unroll
    for (int i = 0; i < 12; ++i) {
        int row = r0 + i;                      // strip 15: clamp (rows pinned)
        if (row > 127) row = 127;
        const float4 va = *reinterpret_cast<const float4*>(img + row * 128 + qc * 4);
        const float4 vb = *reinterpret_cast<const float4*>(img + row * 128 + qc * 4 + 4);
        const float iv[8] = {va.x, va.y, va.z, va.w, vb.x, vb.y, vb.z, vb.w};
        #pragma unroll
        for (int r = 0; r < 8; ++r) {
            const int ki = i - r;
            if (ki >= 0 && ki < 5) {
                #pragma unroll
                for (int j = 0; j < 5; ++j) {
                    const float w = wreg[ki * 5 + j];
                    #pragma unroll
                    for (int c = 0; c < 4; ++c) xs[r][c] = fmaf(w, iv[j + c], xs[r][c]);
                }
            }
        }
    }

    // xs = -log2e * x; pin idle lanes / out-of-image rows to +60 -> q ~ 1e-18
    #pragma unroll
    for (int r = 0; r < 8; ++r)
        #pragma unroll
        for (int c = 0; c < 4; ++c)
            xs[r][c] = (colAct && (r0 + r) < 124) ? (-LOG2E) * xs[r][c] : 60.f;

    // permanent zero guard rows (rows 0 and 33 of both halo buffers);
    // fenced before first halo read by iter-0's barrier
    if (tid < 128) {
        smem[tid] = 0.f;         smem[33 * 128 + tid] = 0.f;
        smem[HBSZ + tid] = 0.f;  smem[HBSZ + 33 * 128 + tid] = 0.f;
    }

    // q0 = sigmoid(x)
    float q[8][4];
    #pragma unroll
    for (int r = 0; r < 8; ++r)
        #pragma unroll
        for (int c = 0; c < 4; ++c) q[r][c] = sigq(0.f, xs[r][c]);

    // halo row offsets (stride-128 rows inside a 34-row sub-buffer)
    const int iwT = (2 * S + 1) * 128 + qc * 4;   // own top h row
    const int iwB = (2 * S + 2) * 128 + qc * 4;   // own bottom h row
    const int irU = (2 * S) * 128 + qc * 4;       // up-neighbor h row
    const int irD = (2 * S + 3) * 128 + qc * 4;   // down-neighbor h row

    for (int it = 0; it < CRF1_ITERS; ++it) {
        float* hb = &smem[(it & 1) ? HBSZ : 0];
        // horizontal 3-sums in registers (edges via shuffle; lane 31/63 hold
        // q~0 so strip edges are automatically zero). q dies here.
        float h[8][4];
        #pragma unroll
        for (int r = 0; r < 8; ++r) {
            const float ql = __shfl(q[r][3], ln - 1);
            const float qr = __shfl(q[r][0], ln + 1);
            const float p01 = q[r][0] + q[r][1];
            const float p12 = q[r][1] + q[r][2];
            const float p23 = q[r][2] + q[r][3];
            h[r][0] = ql  + p01;
            h[r][1] = p01 + q[r][2];
            h[r][2] = p12 + q[r][3];
            h[r][3] = p23 + qr;
        }
        if (colAct) {
            *reinterpret_cast<float4*>(&hb[iwT]) = make_float4(h[0][0], h[0][1], h[0][2], h[0][3]);
            *reinterpret_cast<float4*>(&hb[iwB]) = make_float4(h[7][0], h[7][1], h[7][2], h[7][3]);
        }
        __syncthreads();   // the ONLY barrier in the iteration
        const float4 hu4 = *reinterpret_cast<const float4*>(&hb[irU]);
        const float4 hd4 = *reinterpret_cast<const float4*>(&hb[irD]);
        const float hu[4] = {hu4.x, hu4.y, hu4.z, hu4.w};
        const float hd[4] = {hd4.x, hd4.y, hd4.z, hd4.w};
        // vertical 3-sums + sigmoid, in registers
        #pragma unroll
        for (int c = 0; c < 4; ++c) {
            const float p01 = h[0][c] + h[1][c];
            const float p12 = h[1][c] + h[2][c];
            const float p23 = h[2][c] + h[3][c];
            const float p34 = h[3][c] + h[4][c];
            const float p45 = h[4][c] + h[5][c];
            const float p56 = h[5][c] + h[6][c];
            const float p67 = h[6][c] + h[7][c];
            q[0][c] = sigq(hu[c] + p01,  xs[0][c]);
            q[1][c] = sigq(p01 + h[2][c], xs[1][c]);
            q[2][c] = sigq(p12 + h[3][c], xs[2][c]);
            q[3][c] = sigq(p23 + h[4][c], xs[3][c]);
            q[4][c] = sigq(p34 + h[5][c], xs[4][c]);
            q[5][c] = sigq(p45 + h[6][c], xs[5][c]);
            q[6][c] = sigq(p56 + h[7][c], xs[6][c]);
            q[7][c] = sigq(p67 + hd[c],   xs[7][c]);
        }
        // no trailing barrier: next iter writes the OTHER buffer; reuse of
        // THIS buffer (iter+2) is fenced by iter+1's barrier.
    }
    __syncthreads();   // last halo reads complete before vmax overwrite

    // ---- in-register vertical pool maxes -> vmax[41][132] / aux[16][132].
    // Phase = r0 % 3 selects a static pattern (no runtime q indexing).
    // Bottom-partial / full pool rows -> main vmax[p]; top-partial -> aux[S].
    if (colAct) {
        const int p0 = r0 / 3;
        const int ph = r0 % 3;
        const int co = qc * 4;
        if (ph == 0) {
            // vmax[p0]=rows 0-2, [p0+1]=rows 3-5, [p0+2]=rows 6-7 (partial)
            *reinterpret_cast<float4*>(&smem[p0 * 132 + co]) = make_float4(
                max3f(q[0][0], q[1][0], q[2][0]), max3f(q[0][1], q[1][1], q[2][1]),
                max3f(q[0][2], q[1][2], q[2][2]), max3f(q[0][3], q[1][3], q[2][3]));
            if (p0 + 1 <= 40)
                *reinterpret_cast<float4*>(&smem[(p0 + 1) * 132 + co]) = make_float4(
                    max3f(q[3][0], q[4][0], q[5][0]), max3f(q[3][1], q[4][1], q[5][1]),
                    max3f(q[3][2], q[4][2], q[5][2]), max3f(q[3][3], q[4][3], q[5][3]));
            if (p0 + 2 <= 40)
                *reinterpret_cast<float4*>(&smem[(p0 + 2) * 132 + co]) = make_float4(
                    fmaxf(q[6][0], q[7][0]), fmaxf(q[6][1], q[7][1]),
                    fmaxf(q[6][2], q[7][2]), fmaxf(q[6][3], q[7][3]));
        } else if (ph == 1) {
            // aux[S]=rows 0-1 (top-partial), vmax[p0+1]=rows 2-4, [p0+2]=rows 5-7
            *reinterpret_cast<float4*>(&smem[AUXO + S * 132 + co]) = make_float4(
                fmaxf(q[0][0], q[1][0]), fmaxf(q[0][1], q[1][1]),
                fmaxf(q[0][2], q[1][2]), fmaxf(q[0][3], q[1][3]));
            *reinterpret_cast<float4*>(&smem[(p0 + 1) * 132 + co]) = make_float4(
                max3f(q[2][0], q[3][0], q[4][0]), max3f(q[2][1], q[3][1], q[4][1]),
                max3f(q[2][2], q[3][2], q[4][2]), max3f(q[2][3], q[3][3], q[4][3]));
            *reinterpret_cast<float4*>(&smem[(p0 + 2) * 132 + co]) = make_float4(
                max3f(q[5][0], q[6][0], q[7][0]), max3f(q[5][1], q[6][1], q[7][1]),
                max3f(q[5][2], q[6][2], q[7][2]), max3f(q[5][3], q[6][3], q[7][3]));
        } else {
            // aux[S]=row 0 (top-partial), vmax[p0+1]=rows 1-3, [p0+2]=rows 4-6,
            // vmax[p0+3]=row 7 (bottom-partial)
            *reinterpret_cast<float4*>(&smem[AUXO + S * 132 + co]) =
                make_float4(q[0][0], q[0][1], q[0][2], q[0][3]);
            *reinterpret_cast<float4*>(&smem[(p0 + 1) * 132 + co]) = make_float4(
                max3f(q[1][0], q[2][0], q[3][0]), max3f(q[1][1], q[2][1], q[3][1]),
                max3f(q[1][2], q[2][2], q[3][2]), max3f(q[1][3], q[2][3], q[3][3]));
            *reinterpret_cast<float4*>(&smem[(p0 + 2) * 132 + co]) = make_float4(
                max3f(q[4][0], q[5][0], q[6][0]), max3f(q[4][1], q[5][1], q[6][1]),
                max3f(q[4][2], q[5][2], q[6][2]), max3f(q[4][3], q[5][3], q[6][3]));
            *reinterpret_cast<float4*>(&smem[(p0 + 3) * 132 + co]) =
                make_float4(q[7][0], q[7][1], q[7][2], q[7][3]);
        }
    }
    __syncthreads();

    // ---- horizontal 3-max + boundary-aux combine -> 41x41 output ----
    for (int p = tid; p < 1681; p += 512) {
        const int pr = p / 41;
        const int pc = p - pr * 41;
        const float* vrow = &smem[pr * 132 + 3 * pc];
        float m = max3f(vrow[0], vrow[1], vrow[2]);
        const int s1 = (3 * pr) >> 3;
        const int s2 = (3 * pr + 2) >> 3;
        if (s1 != s2) {   // boundary pool row: combine top-partial owner
            const float* arow = &smem[AUXO + s2 * 132 + 3 * pc];
            m = fmaxf(m, max3f(arow[0], arow[1], arow[2]));
        }
        mp1[(size_t)blk * 1681 + p] = m;
    }
}

// ---------------------------------------------------------------------------
// Kernel 2a: conv2 (5x5 over 32 ch) + BN2 -> logits [128,10,37,37].
// (round-14 version, control) grid (b, quarter) = 512 blocks -> 2 blocks/CU.
// ---------------------------------------------------------------------------
__global__ __launch_bounds__(512) void k2a_conv2(
    const float* __restrict__ mp1,   // [128,32,41,41]
    const float* __restrict__ w2,    // [10,32,5,5]
    const float* __restrict__ b2,
    const float* __restrict__ g2,
    const float* __restrict__ be2,
    const float* __restrict__ m2,
    const float* __restrict__ v2,
    float* __restrict__ logit)       // [128,10,37,37]
{
    __shared__ float sb[2][576];     // 574 used per buffer

    const int blk = blockIdx.x;      // b*4 + qd
    const int b   = blk >> 2;
    const int qd  = blk & 3;
    const int tid = threadIdx.x;
    const int limit = (qd < 3) ? 343 : 340;   // 3*343 + 340 = 1369
    const bool on = (tid < limit);
    const int px = qd * 343 + (on ? tid : 0);
    const int pr = px / 37;
    const int pc = px - pr * 37;
    const int R0 = qd * 9;           // panel top row; quarter pr range fits
    const int lr = pr - R0;          // local row in [0,9]; window lr..lr+4<=13

    const float* ibase = mp1 + (size_t)b * 32 * 1681 + R0 * 41;

    // stage ic=0 (574 floats over 512 threads)
    sb[0][tid] = ibase[tid];
    if (tid < 62) sb[0][512 + tid] = ibase[512 + tid];
    __syncthreads();

    float acc[10] = {};
    for (int ic = 0; ic < 32; ++ic) {
        // issue next panel's loads first (latency hides under compute)
        if (ic < 31) {
            const float* src = ibase + (size_t)(ic + 1) * 1681;
            float* nb = sb[(ic + 1) & 1];
            nb[tid] = src[tid];
            if (tid < 62) nb[512 + tid] = src[512 + tid];
        }
        const float* cur = sb[ic & 1];
        const float* wb  = w2 + ic * 25;
        if (on) {
            const float* wloc = &cur[lr * 41 + pc];
            float win[25];
            #pragma unroll
            for (int i = 0; i < 5; ++i)
                #pragma unroll
                for (int j = 0; j < 5; ++j) win[i * 5 + j] = wloc[i * 41 + j];
            #pragma unroll
            for (int o = 0; o < 10; ++o) {
                float a = acc[o];
                #pragma unroll
                for (int k = 0; k < 25; ++k) a = fmaf(win[k], wb[o * 800 + k], a);
                acc[o] = a;
            }
        }
        __syncthreads();   // stage writes visible; cur reads done
    }

    if (on) {
        #pragma unroll
        for (int o = 0; o < 10; ++o) {
            const float A  = g2[o] * rsqrtf(v2[o] + 1e-5f);
            const float Bc = (b2[o] - m2[o]) * A + be2[o];
            logit[((size_t)b * 10 + o) * 1369 + px] = fmaf(acc[o], A, Bc);
        }
    }
}

// ---------------------------------------------------------------------------
// Kernel 2b: sigmoid-CRF(4 iters) on 37x37 + maxpool 2x2/2 + mean -> [128,10]
// Double-buffered q planes -> ONE barrier per iteration. (unchanged)
// ---------------------------------------------------------------------------
__global__ __launch_bounds__(512) void k2b_crf_pool(
    const float* __restrict__ logit, // [128,10,37,37]
    float* __restrict__ cls)         // [128,10]
{
    __shared__ float qb[2][1600];    // 39 rows x stride 40, px (r,c) @ (r+1)*40+c+1
    __shared__ float wred[8];

    const int blk = blockIdx.x;      // b*10 + oc
    const int tid = threadIdx.x;

    for (int i = tid; i < 1600; i += 512) { qb[0][i] = 0.f; qb[1][i] = 0.f; }

    int   pr[3], pc[3];
    bool  pa[3];
    float xr[3], qc_[3];
    #pragma unroll
    for (int s = 0; s < 3; ++s) {
        const int p = tid + s * 512;
        pa[s] = (p < 1369);
        const int p2 = pa[s] ? p : 0;
        pr[s] = p2 / 37;
        pc[s] = p2 - pr[s] * 37;
        xr[s] = pa[s] ? logit[(size_t)blk * 1369 + p2] : 0.f;
        qc_[s] = sigm(xr[s]);
    }
    __syncthreads();   // zero-fill complete
    #pragma unroll
    for (int s = 0; s < 3; ++s) if (pa[s]) qb[0][(pr[s] + 1) * 40 + pc[s] + 1] = qc_[s];
    __syncthreads();

    for (int it = 0; it < CRF2_ITERS; ++it) {
        const float* cur = qb[it & 1];
        float* nxt = qb[(it + 1) & 1];
        float qn[3] = {};
        #pragma unroll
        for (int s = 0; s < 3; ++s) if (pa[s]) {
            const float* p = &cur[(pr[s] + 1) * 40 + pc[s] + 1];
            const float ss = p[-41] + p[-40] + p[-39]
                           + p[-1]  + qc_[s] + p[1]
                           + p[39]  + p[40]  + p[41];
            qn[s] = sigm(fmaf(ss, 1.f / 9.f, xr[s]));
        }
        #pragma unroll
        for (int s = 0; s < 3; ++s) if (pa[s]) {
            qc_[s] = qn[s];
            nxt[(pr[s] + 1) * 40 + pc[s] + 1] = qn[s];
        }
        __syncthreads();   // nxt visible; cur reads done before overwrite
    }

    const float* fin = qb[CRF2_ITERS & 1];
    float val = 0.f;
    if (tid < 324) {
        const int r2 = tid / 18;
        const int c2 = tid - r2 * 18;
        const float* p = &fin[(2 * r2 + 1) * 40 + 2 * c2 + 1];
        val = fmaxf(fmaxf(p[0], p[1]), fmaxf(p[40], p[41]));
    }
    #pragma unroll
    for (int off = 32; off > 0; off >>= 1) val += __shfl_down(val, off);
    if ((tid & 63) == 0) wred[tid >> 6] = val;
    __syncthreads();
    if (tid == 0) {
        float ss = 0.f;
        #pragma unroll
        for (int w = 0; w < 8; ++w) ss += wred[w];
        cls[blk] = ss * (1.0f / 324.0f);
    }
}

// ---------------------------------------------------------------------------
// Kernel 3: log_softmax over 10 classes, 128 rows.
// ---------------------------------------------------------------------------
__global__ void k3_logsoftmax(const float* __restrict__ cls, float* __restrict__ out)
{
    const int t = threadIdx.x;
    float v[10];
    float m = -1e30f;
    #pragma unroll
    for (int c = 0; c < 10; ++c) { v[c] = cls[t * 10 + c]; m = fmaxf(m, v[c]); }
    float ss = 0.f;
    #pragma unroll
    for (int c = 0; c < 10; ++c) ss += __expf(v[c] - m);
    const float l = m + logf(ss);
    #pragma unroll
    for (int c = 0; c < 10; ++c) out[t * 10 + c] = v[c] - l;
}

extern "C" void kernel_launch(void* const* d_in, const int* in_sizes, int n_in,
                              void* d_out, int out_size, void* d_ws, size_t ws_size,
                              hipStream_t stream)
{
    const float* x   = (const float*)d_in[0];
    const float* w1  = (const float*)d_in[1];
    const float* b1  = (const float*)d_in[2];
    const float* g1  = (const float*)d_in[3];
    const float* be1 = (const float*)d_in[4];
    const float* m1  = (const float*)d_in[5];
    const float* v1  = (const float*)d_in[6];
    const float* w2  = (const float*)d_in[7];
    const float* b2  = (const float*)d_in[8];
    const float* g2  = (const float*)d_in[9];
    const float* be2 = (const float*)d_in[10];
    const float* m2  = (const float*)d_in[11];
    const float* v2  = (const float*)d_in[12];

    float* mp1   = (float*)d_ws;
    float* logit = mp1 + 6885376;
    float* cls   = logit + 1752320;
    float* out   = (float*)d_out;

    k1_conv_crf_pool<<<4096, 512, 0, stream>>>(x, w1, b1, g1, be1, m1, v1, mp1);
    k2a_conv2<<<512, 512, 0, stream>>>(mp1, w2, b2, g2, be2, m2, v2, logit);
    k2b_crf_pool<<<1280, 512, 0, stream>>>(logit, cls);
    k3_logsoftmax<<<1, 128, 0, stream>>>(cls, out);
}